// Round 2
// baseline (1348.548 us; speedup 1.0000x reference)
//
#include <hip/hip_runtime.h>
#include <hip/hip_bf16.h>

typedef __hip_bfloat16 bf16;
typedef __attribute__((ext_vector_type(8))) short short8;
typedef __attribute__((ext_vector_type(4))) short short4v;
typedef __attribute__((ext_vector_type(4))) float floatx4;

#define BQ 8192
#define ND 9
#define DD 1024
#define HH 4096
#define MM 32768  // 4*BQ

__device__ __forceinline__ short f2bf(float f) {
  unsigned u = __float_as_uint(f);
  u = (u + 0x7fff + ((u >> 16) & 1)) >> 16;  // RNE
  return (short)u;
}

// async global -> LDS, 16B per lane; LDS dest is wave-uniform base + lane*16
__device__ __forceinline__ void async16(const void* g, void* l) {
  __builtin_amdgcn_global_load_lds(
      (const __attribute__((address_space(1))) void*)g,
      (__attribute__((address_space(3))) void*)l, 16, 0, 0);
}

// ---------------------------------------------------------------------------
// Kernel 1: build X (M x D) aggregation rows. fp32 in, bf16 out.
//  t_idx 0 (t=2): 0.1*e2 - 3*e3 + 3*e4
//  t_idx 1 (t=4): 3*e2 + 3*e3 + 0.1*e4 - 3*e5 + 3*e6
//  t_idx 2 (t=6): 3*e4 + 3*e5 + 0.1*e6 - 3*e7 + 3*e8
//  t_idx 3 (t=8): 3*e6 + 3*e7 + 0.1*e8
// ---------------------------------------------------------------------------
__global__ __launch_bounds__(256) void build_x(const float* __restrict__ emb,
                                               bf16* __restrict__ X) {
  int gid = blockIdx.x * 256 + threadIdx.x;   // one thread = 4 elements
  int m = gid >> 8;                           // D/4 = 256 chunks/row
  int d = (gid & 255) * 4;
  int t = m >> 13;                            // m / 8192
  int b = m & (BQ - 1);
  const float* base = emb + (size_t)b * (ND * DD) + d;

  float acc[4] = {0.f, 0.f, 0.f, 0.f};
  auto addk = [&](int k, float c) {
    float4 v = *(const float4*)(base + k * DD);
    acc[0] += c * v.x; acc[1] += c * v.y; acc[2] += c * v.z; acc[3] += c * v.w;
  };

  switch (t) {
    case 0: addk(2, 0.1f); addk(3, -3.f); addk(4, 3.f); break;
    case 1: addk(2, 3.f); addk(3, 3.f); addk(4, 0.1f); addk(5, -3.f); addk(6, 3.f); break;
    case 2: addk(4, 3.f); addk(5, 3.f); addk(6, 0.1f); addk(7, -3.f); addk(8, 3.f); break;
    default: addk(6, 3.f); addk(7, 3.f); addk(8, 0.1f); break;
  }

  short4v o;
#pragma unroll
  for (int i = 0; i < 4; ++i) o[i] = f2bf(acc[i]);
  *(short4v*)(X + (size_t)m * DD + d) = o;
}

// ---------------------------------------------------------------------------
// Kernel 2: transpose fp32 (rows x cols) -> bf16 (cols x rows)
// ---------------------------------------------------------------------------
__global__ void transpose_f2b(const float* __restrict__ src, bf16* __restrict__ dst,
                              int rows, int cols) {
  __shared__ float t[32][33];
  int c0 = blockIdx.x * 32, r0 = blockIdx.y * 32;
  int tx = threadIdx.x, ty = threadIdx.y;
  t[ty][tx] = src[(size_t)(r0 + ty) * cols + (c0 + tx)];
  __syncthreads();
  short v = f2bf(t[tx][ty]);
  dst[(size_t)(c0 + ty) * rows + (r0 + tx)] = *(bf16*)&v;
}

// ---------------------------------------------------------------------------
// Kernel 3: C = act(A @ Bt^T + bias). A: MxK bf16 row-major, Bt: NxK bf16
// row-major, bias fp32, C is OutT (bf16 intermediate / fp32 final).
// 128x128 tile, BK=64, 4 waves x (4x4) 16x16x32 bf16 MFMA. m97 structure.
// ---------------------------------------------------------------------------
template <int RELU, typename OutT>
__global__ __launch_bounds__(256) void gemm_bt(const bf16* __restrict__ A,
                                               const bf16* __restrict__ Bt,
                                               const float* __restrict__ bias,
                                               OutT* __restrict__ C,
                                               int M, int N, int K) {
  __shared__ bf16 As[128 * 64];
  __shared__ bf16 Bs[128 * 64];
  int tid = threadIdx.x;
  int lane = tid & 63;
  int wave = tid >> 6;
  int wm = wave >> 1, wn = wave & 1;
  int m0 = blockIdx.y * 128, n0 = blockIdx.x * 128;

  floatx4 zero = {0.f, 0.f, 0.f, 0.f};
  floatx4 acc[4][4];
#pragma unroll
  for (int i = 0; i < 4; ++i)
#pragma unroll
    for (int j = 0; j < 4; ++j) acc[i][j] = zero;

  int srow = lane >> 3;        // row within 8-row chunk
  int scol = (lane & 7) * 8;   // k-element offset within 64

  for (int k0 = 0; k0 < K; k0 += 64) {
#pragma unroll
    for (int j = 0; j < 4; ++j) {
      int q = wave * 4 + j;          // chunk 0..15, 8 rows each
      int row = q * 8 + srow;
      const bf16* ga = A + (size_t)(m0 + row) * K + (k0 + scol);
      const bf16* gb = Bt + (size_t)(n0 + row) * K + (k0 + scol);
      async16(ga, (char*)As + q * 1024);
      async16(gb, (char*)Bs + q * 1024);
    }
    __syncthreads();   // compiler drains vmcnt before s_barrier

#pragma unroll
    for (int ks = 0; ks < 64; ks += 32) {
      short8 af[4], bf[4];
      int kk = ks + (lane >> 4) * 8;
      int rbase = wm * 64 + (lane & 15);
      int nbase = wn * 64 + (lane & 15);
#pragma unroll
      for (int i = 0; i < 4; ++i) af[i] = *(const short8*)(As + (rbase + i * 16) * 64 + kk);
#pragma unroll
      for (int j = 0; j < 4; ++j) bf[j] = *(const short8*)(Bs + (nbase + j * 16) * 64 + kk);
#pragma unroll
      for (int i = 0; i < 4; ++i)
#pragma unroll
        for (int j = 0; j < 4; ++j)
          acc[i][j] = __builtin_amdgcn_mfma_f32_16x16x32_bf16(af[i], bf[j], acc[i][j], 0, 0, 0);
    }
    __syncthreads();   // protect LDS before next staging overwrite
  }

  // Epilogue: C/D layout col = lane&15, row = (lane>>4)*4 + r
  int crow = m0 + wm * 64 + ((lane >> 4) << 2);
  int ccol0 = n0 + wn * 64 + (lane & 15);
#pragma unroll
  for (int j = 0; j < 4; ++j) {
    int col = ccol0 + j * 16;
    float bv = bias[col];
#pragma unroll
    for (int i = 0; i < 4; ++i) {
#pragma unroll
      for (int r = 0; r < 4; ++r) {
        float v = acc[i][j][r] + bv;
        if (RELU) v = fmaxf(v, 0.f);
        if constexpr (sizeof(OutT) == 2) {
          short s = f2bf(v);
          C[(size_t)(crow + i * 16 + r) * N + col] = *(OutT*)&s;
        } else {
          C[(size_t)(crow + i * 16 + r) * N + col] = *(OutT*)&v;
        }
      }
    }
  }
}

// ---------------------------------------------------------------------------
extern "C" void kernel_launch(void* const* d_in, const int* in_sizes, int n_in,
                              void* d_out, int out_size, void* d_ws, size_t ws_size,
                              hipStream_t stream) {
  const float* emb = (const float*)d_in[0];
  const float* W1  = (const float*)d_in[1];
  const float* b1  = (const float*)d_in[2];
  const float* W2  = (const float*)d_in[3];
  const float* b2  = (const float*)d_in[4];
  float* out = (float*)d_out;

  char* ws = (char*)d_ws;
  // ws layout: X (64MB) | Y (256MB) | W1t (8MB) | W2t (8MB)  => 336MB
  bf16* X   = (bf16*)(ws);
  bf16* Y   = (bf16*)(ws + (size_t)67108864);
  bf16* W1t = (bf16*)(ws + (size_t)67108864 + (size_t)268435456);
  bf16* W2t = (bf16*)(ws + (size_t)67108864 + (size_t)268435456 + (size_t)8388608);

  // 1) aggregation rows (fp32 -> bf16)
  build_x<<<dim3((MM * DD / 4) / 256), dim3(256), 0, stream>>>(emb, X);
  // 2) transpose weights to N x K bf16 for B^T staging
  transpose_f2b<<<dim3(HH / 32, DD / 32), dim3(32, 32), 0, stream>>>(W1, W1t, DD, HH);
  transpose_f2b<<<dim3(DD / 32, HH / 32), dim3(32, 32), 0, stream>>>(W2, W2t, HH, DD);
  // 3) Y = relu(X @ W1 + b1), bf16
  gemm_bt<1, bf16><<<dim3(HH / 128, MM / 128), dim3(256), 0, stream>>>(X, W1t, b1, Y, MM, HH, DD);
  // 4) out = Y @ W2 + b2, fp32
  gemm_bt<0, float><<<dim3(DD / 128, MM / 128), dim3(256), 0, stream>>>(Y, W2t, b2, out, MM, DD, HH);
}

// Round 3
// 1288.728 us; speedup vs baseline: 1.0464x; 1.0464x over previous
//
#include <hip/hip_runtime.h>
#include <hip/hip_bf16.h>

typedef __hip_bfloat16 bf16;
typedef __attribute__((ext_vector_type(8))) short short8;
typedef __attribute__((ext_vector_type(4))) short short4v;
typedef __attribute__((ext_vector_type(4))) float floatx4;

#define BQ 8192
#define ND 9
#define DD 1024
#define HH 4096
#define MM 32768  // 4*BQ

__device__ __forceinline__ short f2bf(float f) {
  unsigned u = __float_as_uint(f);
  u = (u + 0x7fff + ((u >> 16) & 1)) >> 16;  // RNE
  return (short)u;
}

// async global -> LDS, 16B per lane; LDS dest is wave-uniform base + lane*16
__device__ __forceinline__ void async16(const void* g, void* l) {
  __builtin_amdgcn_global_load_lds(
      (const __attribute__((address_space(1))) void*)g,
      (__attribute__((address_space(3))) void*)l, 16, 0, 0);
}

// ---------------------------------------------------------------------------
// Kernel 1: build X (M x D) aggregation rows. fp32 in, bf16 out.
// ---------------------------------------------------------------------------
__global__ __launch_bounds__(256) void build_x(const float* __restrict__ emb,
                                               bf16* __restrict__ X) {
  int gid = blockIdx.x * 256 + threadIdx.x;   // one thread = 4 elements
  int m = gid >> 8;                           // D/4 = 256 chunks/row
  int d = (gid & 255) * 4;
  int t = m >> 13;                            // m / 8192
  int b = m & (BQ - 1);
  const float* base = emb + (size_t)b * (ND * DD) + d;

  float acc[4] = {0.f, 0.f, 0.f, 0.f};
  auto addk = [&](int k, float c) {
    float4 v = *(const float4*)(base + k * DD);
    acc[0] += c * v.x; acc[1] += c * v.y; acc[2] += c * v.z; acc[3] += c * v.w;
  };

  switch (t) {
    case 0: addk(2, 0.1f); addk(3, -3.f); addk(4, 3.f); break;
    case 1: addk(2, 3.f); addk(3, 3.f); addk(4, 0.1f); addk(5, -3.f); addk(6, 3.f); break;
    case 2: addk(4, 3.f); addk(5, 3.f); addk(6, 0.1f); addk(7, -3.f); addk(8, 3.f); break;
    default: addk(6, 3.f); addk(7, 3.f); addk(8, 0.1f); break;
  }

  short4v o;
#pragma unroll
  for (int i = 0; i < 4; ++i) o[i] = f2bf(acc[i]);
  *(short4v*)(X + (size_t)m * DD + d) = o;
}

// ---------------------------------------------------------------------------
// Kernel 2: transpose fp32 (rows x cols) -> bf16 (cols x rows)
// ---------------------------------------------------------------------------
__global__ void transpose_f2b(const float* __restrict__ src, bf16* __restrict__ dst,
                              int rows, int cols) {
  __shared__ float t[32][33];
  int c0 = blockIdx.x * 32, r0 = blockIdx.y * 32;
  int tx = threadIdx.x, ty = threadIdx.y;
  t[ty][tx] = src[(size_t)(r0 + ty) * cols + (c0 + tx)];
  __syncthreads();
  short v = f2bf(t[tx][ty]);
  dst[(size_t)(c0 + ty) * rows + (r0 + tx)] = *(bf16*)&v;
}

// ---------------------------------------------------------------------------
// Kernel 3: C = act(A @ Bt^T + bias). A: MxK bf16 row-major, Bt: NxK bf16
// row-major, bias fp32, C is OutT (bf16 intermediate / fp32 final).
// 128x128 tile, BK=64, 4 waves x (4x4) 16x16x32 MFMA.
// LDS layout XOR-swizzled: row r's logical 16B k-slot s lives at physical
// slot s^(r&7). Staging achieves this by permuting the *global* source
// column per lane (async16's LDS dest is fixed at base+lane*16).
// Fragment reads then hit 8 distinct bank groups -> 2-way only (free).
// ---------------------------------------------------------------------------
template <int RELU, typename OutT>
__global__ __launch_bounds__(256) void gemm_bt(const bf16* __restrict__ A,
                                               const bf16* __restrict__ Bt,
                                               const float* __restrict__ bias,
                                               OutT* __restrict__ C,
                                               int M, int N, int K) {
  __shared__ bf16 As[128 * 64];
  __shared__ bf16 Bs[128 * 64];
  int tid = threadIdx.x;
  int lane = tid & 63;
  int wave = tid >> 6;
  int wm = wave >> 1, wn = wave & 1;
  int m0 = blockIdx.y * 128, n0 = blockIdx.x * 128;

  floatx4 zero = {0.f, 0.f, 0.f, 0.f};
  floatx4 acc[4][4];
#pragma unroll
  for (int i = 0; i < 4; ++i)
#pragma unroll
    for (int j = 0; j < 4; ++j) acc[i][j] = zero;

  int srow = lane >> 3;                         // row within 8-row chunk
  int scol = ((lane & 7) ^ srow) * 8;           // XOR-swizzled source k-offset

  for (int k0 = 0; k0 < K; k0 += 64) {
#pragma unroll
    for (int j = 0; j < 4; ++j) {
      int q = wave * 4 + j;          // chunk 0..15, 8 rows each
      int row = q * 8 + srow;
      const bf16* ga = A + (size_t)(m0 + row) * K + (k0 + scol);
      const bf16* gb = Bt + (size_t)(n0 + row) * K + (k0 + scol);
      async16(ga, (char*)As + q * 1024);
      async16(gb, (char*)Bs + q * 1024);
    }
    __syncthreads();   // compiler drains vmcnt before s_barrier

#pragma unroll
    for (int ks = 0; ks < 64; ks += 32) {
      short8 af[4], bf[4];
      int rr = lane & 7;                     // row&7 for all fragment rows
      int sl = (ks >> 3) + (lane >> 4);      // logical 16B slot (0..7)
      int ps = (sl ^ rr) << 3;               // physical slot -> element offset
      int rbase = wm * 64 + (lane & 15);
      int nbase = wn * 64 + (lane & 15);
#pragma unroll
      for (int i = 0; i < 4; ++i) {
        int row = rbase + i * 16;
        af[i] = *(const short8*)(As + (row >> 3) * 512 + rr * 64 + ps);
      }
#pragma unroll
      for (int j = 0; j < 4; ++j) {
        int row = nbase + j * 16;
        bf[j] = *(const short8*)(Bs + (row >> 3) * 512 + rr * 64 + ps);
      }
#pragma unroll
      for (int i = 0; i < 4; ++i)
#pragma unroll
        for (int j = 0; j < 4; ++j)
          acc[i][j] = __builtin_amdgcn_mfma_f32_16x16x32_bf16(af[i], bf[j], acc[i][j], 0, 0, 0);
    }
    __syncthreads();   // protect LDS before next staging overwrite
  }

  // Epilogue: C/D layout col = lane&15, row = (lane>>4)*4 + r
  int crow = m0 + wm * 64 + ((lane >> 4) << 2);
  int ccol0 = n0 + wn * 64 + (lane & 15);
#pragma unroll
  for (int j = 0; j < 4; ++j) {
    int col = ccol0 + j * 16;
    float bv = bias[col];
#pragma unroll
    for (int i = 0; i < 4; ++i) {
#pragma unroll
      for (int r = 0; r < 4; ++r) {
        float v = acc[i][j][r] + bv;
        if (RELU) v = fmaxf(v, 0.f);
        if constexpr (sizeof(OutT) == 2) {
          short s = f2bf(v);
          C[(size_t)(crow + i * 16 + r) * N + col] = *(OutT*)&s;
        } else {
          C[(size_t)(crow + i * 16 + r) * N + col] = *(OutT*)&v;
        }
      }
    }
  }
}

// ---------------------------------------------------------------------------
extern "C" void kernel_launch(void* const* d_in, const int* in_sizes, int n_in,
                              void* d_out, int out_size, void* d_ws, size_t ws_size,
                              hipStream_t stream) {
  const float* emb = (const float*)d_in[0];
  const float* W1  = (const float*)d_in[1];
  const float* b1  = (const float*)d_in[2];
  const float* W2  = (const float*)d_in[3];
  const float* b2  = (const float*)d_in[4];
  float* out = (float*)d_out;

  char* ws = (char*)d_ws;
  // ws layout: X (64MB) | Y (256MB) | W1t (8MB) | W2t (8MB)  => 336MB
  bf16* X   = (bf16*)(ws);
  bf16* Y   = (bf16*)(ws + (size_t)67108864);
  bf16* W1t = (bf16*)(ws + (size_t)67108864 + (size_t)268435456);
  bf16* W2t = (bf16*)(ws + (size_t)67108864 + (size_t)268435456 + (size_t)8388608);

  // 1) aggregation rows (fp32 -> bf16)
  build_x<<<dim3((MM * DD / 4) / 256), dim3(256), 0, stream>>>(emb, X);
  // 2) transpose weights to N x K bf16 for B^T staging
  transpose_f2b<<<dim3(HH / 32, DD / 32), dim3(32, 32), 0, stream>>>(W1, W1t, DD, HH);
  transpose_f2b<<<dim3(DD / 32, HH / 32), dim3(32, 32), 0, stream>>>(W2, W2t, HH, DD);
  // 3) Y = relu(X @ W1 + b1), bf16
  gemm_bt<1, bf16><<<dim3(HH / 128, MM / 128), dim3(256), 0, stream>>>(X, W1t, b1, Y, MM, HH, DD);
  // 4) out = Y @ W2 + b2, fp32
  gemm_bt<0, float><<<dim3(DD / 128, MM / 128), dim3(256), 0, stream>>>(Y, W2t, b2, out, MM, DD, HH);
}

// Round 4
// 1170.230 us; speedup vs baseline: 1.1524x; 1.1013x over previous
//
#include <hip/hip_runtime.h>
#include <hip/hip_bf16.h>

typedef __hip_bfloat16 bf16;
typedef __attribute__((ext_vector_type(8))) short short8;
typedef __attribute__((ext_vector_type(4))) short short4v;
typedef __attribute__((ext_vector_type(16))) float floatx16;

#define BQ 8192
#define ND 9
#define DD 1024
#define HH 4096
#define MM 32768  // 4*BQ

__device__ __forceinline__ short f2bf(float f) {
  unsigned u = __float_as_uint(f);
  u = (u + 0x7fff + ((u >> 16) & 1)) >> 16;  // RNE
  return (short)u;
}

// async global -> LDS, 16B per lane; LDS dest is wave-uniform base + lane*16
__device__ __forceinline__ void async16(const void* g, void* l) {
  __builtin_amdgcn_global_load_lds(
      (const __attribute__((address_space(1))) void*)g,
      (__attribute__((address_space(3))) void*)l, 16, 0, 0);
}

// ---------------------------------------------------------------------------
// Kernel 1: build X (M x D) aggregation rows. fp32 in, bf16 out.
// ---------------------------------------------------------------------------
__global__ __launch_bounds__(256) void build_x(const float* __restrict__ emb,
                                               bf16* __restrict__ X) {
  int gid = blockIdx.x * 256 + threadIdx.x;   // one thread = 4 elements
  int m = gid >> 8;                           // D/4 = 256 chunks/row
  int d = (gid & 255) * 4;
  int t = m >> 13;                            // m / 8192
  int b = m & (BQ - 1);
  const float* base = emb + (size_t)b * (ND * DD) + d;

  float acc[4] = {0.f, 0.f, 0.f, 0.f};
  auto addk = [&](int k, float c) {
    float4 v = *(const float4*)(base + k * DD);
    acc[0] += c * v.x; acc[1] += c * v.y; acc[2] += c * v.z; acc[3] += c * v.w;
  };

  switch (t) {
    case 0: addk(2, 0.1f); addk(3, -3.f); addk(4, 3.f); break;
    case 1: addk(2, 3.f); addk(3, 3.f); addk(4, 0.1f); addk(5, -3.f); addk(6, 3.f); break;
    case 2: addk(4, 3.f); addk(5, 3.f); addk(6, 0.1f); addk(7, -3.f); addk(8, 3.f); break;
    default: addk(6, 3.f); addk(7, 3.f); addk(8, 0.1f); break;
  }

  short4v o;
#pragma unroll
  for (int i = 0; i < 4; ++i) o[i] = f2bf(acc[i]);
  *(short4v*)(X + (size_t)m * DD + d) = o;
}

// ---------------------------------------------------------------------------
// Kernel 2: transpose fp32 (rows x cols) -> bf16 (cols x rows)
// ---------------------------------------------------------------------------
__global__ void transpose_f2b(const float* __restrict__ src, bf16* __restrict__ dst,
                              int rows, int cols) {
  __shared__ float t[32][33];
  int c0 = blockIdx.x * 32, r0 = blockIdx.y * 32;
  int tx = threadIdx.x, ty = threadIdx.y;
  t[ty][tx] = src[(size_t)(r0 + ty) * cols + (c0 + tx)];
  __syncthreads();
  short v = f2bf(t[tx][ty]);
  dst[(size_t)(c0 + ty) * rows + (r0 + tx)] = *(bf16*)&v;
}

// ---------------------------------------------------------------------------
// Kernel 3: C = act(A @ Bt^T + bias). A: MxK bf16 row-major, Bt: NxK bf16
// row-major, bias fp32, C is OutT (bf16 intermediate / fp32 final).
// 128x128 tile, BK=64, 4 waves x (2x2) 32x32x16 MFMA (64x64 per wave).
// LDS XOR-swizzle: row r's logical 16B k-slot s at phys slot s^(r&7);
// staging permutes the global source column (async16 LDS dest is fixed).
// Staging pointers hoisted out of the K-loop (incremented, not rebuilt).
// ---------------------------------------------------------------------------
template <int RELU, typename OutT>
__global__ __launch_bounds__(256) void gemm_bt(const bf16* __restrict__ A,
                                               const bf16* __restrict__ Bt,
                                               const float* __restrict__ bias,
                                               OutT* __restrict__ C,
                                               int M, int N, int K) {
  __shared__ bf16 As[128 * 64];
  __shared__ bf16 Bs[128 * 64];
  int tid = threadIdx.x;
  int lane = tid & 63;
  int wave = tid >> 6;
  int wm = wave >> 1, wn = wave & 1;
  int m0 = blockIdx.y * 128, n0 = blockIdx.x * 128;

  floatx16 acc[2][2];
#pragma unroll
  for (int i = 0; i < 2; ++i)
#pragma unroll
    for (int j = 0; j < 2; ++j)
#pragma unroll
      for (int r = 0; r < 16; ++r) acc[i][j][r] = 0.f;

  int srow = lane >> 3;                         // row within 8-row chunk
  int scol = ((lane & 7) ^ srow) * 8;           // XOR-swizzled source k-offset

  // hoisted staging pointers (advance by BK=64 elements per iter)
  const bf16* ga[4];
  const bf16* gb[4];
#pragma unroll
  for (int j = 0; j < 4; ++j) {
    int row = (wave * 4 + j) * 8 + srow;
    ga[j] = A + (size_t)(m0 + row) * K + scol;
    gb[j] = Bt + (size_t)(n0 + row) * K + scol;
  }

  int rr = lane & 7;
  int mrow = wm * 64 + (lane & 31);             // A fragment row (+i*32)
  int nrow = wn * 64 + (lane & 31);             // B fragment row (+j*32)
  int half = lane >> 5;                         // k-half selector

  for (int k0 = 0; k0 < K; k0 += 64) {
#pragma unroll
    for (int j = 0; j < 4; ++j) {
      int q = wave * 4 + j;
      async16(ga[j], (char*)As + q * 1024);
      async16(gb[j], (char*)Bs + q * 1024);
      ga[j] += 64;
      gb[j] += 64;
    }
    __syncthreads();   // drains vmcnt before s_barrier

#pragma unroll
    for (int ks = 0; ks < 64; ks += 16) {
      int sl = (ks >> 3) + half;                // logical 16B slot 0..7
      int ps = (sl ^ rr) << 3;                  // physical element offset
      short8 af[2], bf[2];
#pragma unroll
      for (int i = 0; i < 2; ++i)
        af[i] = *(const short8*)(As + (mrow + i * 32) * 64 + ps);
#pragma unroll
      for (int j = 0; j < 2; ++j)
        bf[j] = *(const short8*)(Bs + (nrow + j * 32) * 64 + ps);
#pragma unroll
      for (int i = 0; i < 2; ++i)
#pragma unroll
        for (int j = 0; j < 2; ++j)
          acc[i][j] = __builtin_amdgcn_mfma_f32_32x32x16_bf16(af[i], bf[j], acc[i][j], 0, 0, 0);
    }
    __syncthreads();   // protect LDS before next staging overwrite
  }

  // Epilogue: 32x32 C/D layout col = lane&31, row = (r&3) + 8*(r>>2) + 4*half
  int colbase = n0 + wn * 64 + (lane & 31);
  int rowbase = m0 + wm * 64 + 4 * half;
#pragma unroll
  for (int j = 0; j < 2; ++j) {
    int col = colbase + j * 32;
    float bv = bias[col];
#pragma unroll
    for (int i = 0; i < 2; ++i) {
#pragma unroll
      for (int r = 0; r < 16; ++r) {
        int row = rowbase + i * 32 + (r & 3) + 8 * (r >> 2);
        float v = acc[i][j][r] + bv;
        if (RELU) v = fmaxf(v, 0.f);
        if constexpr (sizeof(OutT) == 2) {
          short s = f2bf(v);
          C[(size_t)row * N + col] = *(OutT*)&s;
        } else {
          C[(size_t)row * N + col] = *(OutT*)&v;
        }
      }
    }
  }
}

// ---------------------------------------------------------------------------
extern "C" void kernel_launch(void* const* d_in, const int* in_sizes, int n_in,
                              void* d_out, int out_size, void* d_ws, size_t ws_size,
                              hipStream_t stream) {
  const float* emb = (const float*)d_in[0];
  const float* W1  = (const float*)d_in[1];
  const float* b1  = (const float*)d_in[2];
  const float* W2  = (const float*)d_in[3];
  const float* b2  = (const float*)d_in[4];
  float* out = (float*)d_out;

  char* ws = (char*)d_ws;
  // ws layout: X (64MB) | Y (256MB) | W1t (8MB) | W2t (8MB)  => 336MB
  bf16* X   = (bf16*)(ws);
  bf16* Y   = (bf16*)(ws + (size_t)67108864);
  bf16* W1t = (bf16*)(ws + (size_t)67108864 + (size_t)268435456);
  bf16* W2t = (bf16*)(ws + (size_t)67108864 + (size_t)268435456 + (size_t)8388608);

  // 1) aggregation rows (fp32 -> bf16)
  build_x<<<dim3((MM * DD / 4) / 256), dim3(256), 0, stream>>>(emb, X);
  // 2) transpose weights to N x K bf16 for B^T staging
  transpose_f2b<<<dim3(HH / 32, DD / 32), dim3(32, 32), 0, stream>>>(W1, W1t, DD, HH);
  transpose_f2b<<<dim3(DD / 32, HH / 32), dim3(32, 32), 0, stream>>>(W2, W2t, HH, DD);
  // 3) Y = relu(X @ W1 + b1), bf16
  gemm_bt<1, bf16><<<dim3(HH / 128, MM / 128), dim3(256), 0, stream>>>(X, W1t, b1, Y, MM, HH, DD);
  // 4) out = Y @ W2 + b2, fp32
  gemm_bt<0, float><<<dim3(DD / 128, MM / 128), dim3(256), 0, stream>>>(Y, W2t, b2, out, MM, DD, HH);
}

// Round 5
// 1163.113 us; speedup vs baseline: 1.1594x; 1.0061x over previous
//
#include <hip/hip_runtime.h>
#include <hip/hip_bf16.h>

typedef __hip_bfloat16 bf16;
typedef __attribute__((ext_vector_type(8))) short short8;
typedef __attribute__((ext_vector_type(4))) short short4v;
typedef __attribute__((ext_vector_type(16))) float floatx16;

#define BQ 8192
#define ND 9
#define DD 1024
#define HH 4096
#define MM 32768  // 4*BQ

__device__ __forceinline__ short f2bf(float f) {
  unsigned u = __float_as_uint(f);
  u = (u + 0x7fff + ((u >> 16) & 1)) >> 16;  // RNE
  return (short)u;
}

// async global -> LDS, 16B per lane; LDS dest is wave-uniform base + lane*16
__device__ __forceinline__ void async16(const void* g, void* l) {
  __builtin_amdgcn_global_load_lds(
      (const __attribute__((address_space(1))) void*)g,
      (__attribute__((address_space(3))) void*)l, 16, 0, 0);
}

// ---------------------------------------------------------------------------
// Kernel 1: build X (M x D). One block per batch row b; each thread owns 4
// consecutive d-elements, reads e2..e8 ONCE, emits all 4 target rows.
// Traffic: 229 MB read + 64 MB write (was 536+64).
//  t0 (t=2): 0.1*e2 - 3*e3 + 3*e4
//  t1 (t=4): 3*e2 + 3*e3 + 0.1*e4 - 3*e5 + 3*e6
//  t2 (t=6): 3*e4 + 3*e5 + 0.1*e6 - 3*e7 + 3*e8
//  t3 (t=8): 3*e6 + 3*e7 + 0.1*e8
// ---------------------------------------------------------------------------
__global__ __launch_bounds__(256) void build_x(const float* __restrict__ emb,
                                               bf16* __restrict__ X) {
  int b = blockIdx.x;
  int d = threadIdx.x * 4;
  const float* base = emb + (size_t)b * (ND * DD) + d;

  float e[7][4];  // e[k] = embedding row k+2
#pragma unroll
  for (int k = 0; k < 7; ++k) *(float4*)e[k] = *(const float4*)(base + (k + 2) * DD);

  auto store = [&](int t, const float* v) {
    short4v o;
#pragma unroll
    for (int c = 0; c < 4; ++c) o[c] = f2bf(v[c]);
    *(short4v*)(X + ((size_t)t * BQ + b) * DD + d) = o;
  };

  float o0[4], o1[4], o2[4], o3[4];
#pragma unroll
  for (int c = 0; c < 4; ++c) {
    o0[c] = 0.1f * e[0][c] - 3.f * e[1][c] + 3.f * e[2][c];
    o1[c] = 3.f * e[0][c] + 3.f * e[1][c] + 0.1f * e[2][c] - 3.f * e[3][c] + 3.f * e[4][c];
    o2[c] = 3.f * e[2][c] + 3.f * e[3][c] + 0.1f * e[4][c] - 3.f * e[5][c] + 3.f * e[6][c];
    o3[c] = 3.f * e[4][c] + 3.f * e[5][c] + 0.1f * e[6][c];
  }
  store(0, o0); store(1, o1); store(2, o2); store(3, o3);
}

// ---------------------------------------------------------------------------
// Kernel 2: transpose fp32 (rows x cols) -> bf16 (cols x rows)
// ---------------------------------------------------------------------------
__global__ void transpose_f2b(const float* __restrict__ src, bf16* __restrict__ dst,
                              int rows, int cols) {
  __shared__ float t[32][33];
  int c0 = blockIdx.x * 32, r0 = blockIdx.y * 32;
  int tx = threadIdx.x, ty = threadIdx.y;
  t[ty][tx] = src[(size_t)(r0 + ty) * cols + (c0 + tx)];
  __syncthreads();
  short v = f2bf(t[tx][ty]);
  dst[(size_t)(c0 + ty) * rows + (r0 + tx)] = *(bf16*)&v;
}

// ---------------------------------------------------------------------------
// Kernel 3: C = act(A @ Bt^T + bias). A: MxK bf16 row-major, Bt: NxK bf16
// row-major, bias fp32, C is OutT (bf16 intermediate / fp32 final).
// 128x128 tile, BK=64, 4 waves x (2x2) 32x32x16 MFMA (64x64 per wave).
// LDS XOR-swizzle: row r's logical 16B k-slot s at phys slot s^(r&7);
// staging permutes the global source column (async16 LDS dest is fixed).
// XCD-aware block swizzle: linear block id b -> xcd=b&7 gets a CONTIGUOUS
// chunk of tiles (n-fastest), so the gridx blocks sharing an A-row-stripe
// run temporally adjacent on ONE XCD -> stripe served from that XCD's L2.
// ---------------------------------------------------------------------------
template <int RELU, typename OutT>
__global__ __launch_bounds__(256) void gemm_bt(const bf16* __restrict__ A,
                                               const bf16* __restrict__ Bt,
                                               const float* __restrict__ bias,
                                               OutT* __restrict__ C,
                                               int M, int N, int K, int lognx) {
  __shared__ bf16 As[128 * 64];
  __shared__ bf16 Bs[128 * 64];
  int tid = threadIdx.x;
  int lane = tid & 63;
  int wave = tid >> 6;
  int wm = wave >> 1, wn = wave & 1;

  // XCD swizzle (pure permutation of tile ids; perf heuristic only)
  int G = gridDim.x * gridDim.y;
  int b = blockIdx.y * gridDim.x + blockIdx.x;
  int gb = (b & 7) * (G >> 3) + (b >> 3);
  int ntile = gb & ((1 << lognx) - 1);
  int mtile = gb >> lognx;
  int m0 = mtile * 128, n0 = ntile * 128;

  floatx16 acc[2][2];
#pragma unroll
  for (int i = 0; i < 2; ++i)
#pragma unroll
    for (int j = 0; j < 2; ++j)
#pragma unroll
      for (int r = 0; r < 16; ++r) acc[i][j][r] = 0.f;

  int srow = lane >> 3;                         // row within 8-row chunk
  int scol = ((lane & 7) ^ srow) * 8;           // XOR-swizzled source k-offset

  // hoisted staging pointers (advance by BK=64 elements per iter)
  const bf16* ga[4];
  const bf16* gb_[4];
#pragma unroll
  for (int j = 0; j < 4; ++j) {
    int row = (wave * 4 + j) * 8 + srow;
    ga[j] = A + (size_t)(m0 + row) * K + scol;
    gb_[j] = Bt + (size_t)(n0 + row) * K + scol;
  }

  int rr = lane & 7;
  int mrow = wm * 64 + (lane & 31);             // A fragment row (+i*32)
  int nrow = wn * 64 + (lane & 31);             // B fragment row (+j*32)
  int half = lane >> 5;                         // k-half selector

  for (int k0 = 0; k0 < K; k0 += 64) {
#pragma unroll
    for (int j = 0; j < 4; ++j) {
      int q = wave * 4 + j;
      async16(ga[j], (char*)As + q * 1024);
      async16(gb_[j], (char*)Bs + q * 1024);
      ga[j] += 64;
      gb_[j] += 64;
    }
    __syncthreads();   // drains vmcnt before s_barrier

#pragma unroll
    for (int ks = 0; ks < 64; ks += 16) {
      int sl = (ks >> 3) + half;                // logical 16B slot 0..7
      int ps = (sl ^ rr) << 3;                  // physical element offset
      short8 af[2], bf[2];
#pragma unroll
      for (int i = 0; i < 2; ++i)
        af[i] = *(const short8*)(As + (mrow + i * 32) * 64 + ps);
#pragma unroll
      for (int j = 0; j < 2; ++j)
        bf[j] = *(const short8*)(Bs + (nrow + j * 32) * 64 + ps);
#pragma unroll
      for (int i = 0; i < 2; ++i)
#pragma unroll
        for (int j = 0; j < 2; ++j)
          acc[i][j] = __builtin_amdgcn_mfma_f32_32x32x16_bf16(af[i], bf[j], acc[i][j], 0, 0, 0);
    }
    __syncthreads();   // protect LDS before next staging overwrite
  }

  // Epilogue: 32x32 C/D layout col = lane&31, row = (r&3) + 8*(r>>2) + 4*half
  int colbase = n0 + wn * 64 + (lane & 31);
  int rowbase = m0 + wm * 64 + 4 * half;
#pragma unroll
  for (int j = 0; j < 2; ++j) {
    int col = colbase + j * 32;
    float bv = bias[col];
#pragma unroll
    for (int i = 0; i < 2; ++i) {
#pragma unroll
      for (int r = 0; r < 16; ++r) {
        int row = rowbase + i * 32 + (r & 3) + 8 * (r >> 2);
        float v = acc[i][j][r] + bv;
        if (RELU) v = fmaxf(v, 0.f);
        if constexpr (sizeof(OutT) == 2) {
          short s = f2bf(v);
          C[(size_t)row * N + col] = *(OutT*)&s;
        } else {
          C[(size_t)row * N + col] = *(OutT*)&v;
        }
      }
    }
  }
}

// ---------------------------------------------------------------------------
extern "C" void kernel_launch(void* const* d_in, const int* in_sizes, int n_in,
                              void* d_out, int out_size, void* d_ws, size_t ws_size,
                              hipStream_t stream) {
  const float* emb = (const float*)d_in[0];
  const float* W1  = (const float*)d_in[1];
  const float* b1  = (const float*)d_in[2];
  const float* W2  = (const float*)d_in[3];
  const float* b2  = (const float*)d_in[4];
  float* out = (float*)d_out;

  char* ws = (char*)d_ws;
  // ws layout: X (64MB) | Y (256MB) | W1t (8MB) | W2t (8MB)  => 336MB
  bf16* X   = (bf16*)(ws);
  bf16* Y   = (bf16*)(ws + (size_t)67108864);
  bf16* W1t = (bf16*)(ws + (size_t)67108864 + (size_t)268435456);
  bf16* W2t = (bf16*)(ws + (size_t)67108864 + (size_t)268435456 + (size_t)8388608);

  // 1) aggregation rows (fp32 -> bf16), read-once per embedding vector
  build_x<<<dim3(BQ), dim3(256), 0, stream>>>(emb, X);
  // 2) transpose weights to N x K bf16 for B^T staging
  transpose_f2b<<<dim3(HH / 32, DD / 32), dim3(32, 32), 0, stream>>>(W1, W1t, DD, HH);
  transpose_f2b<<<dim3(DD / 32, HH / 32), dim3(32, 32), 0, stream>>>(W2, W2t, HH, DD);
  // 3) Y = relu(X @ W1 + b1), bf16   (gridDim.x = 32 -> lognx = 5)
  gemm_bt<1, bf16><<<dim3(HH / 128, MM / 128), dim3(256), 0, stream>>>(X, W1t, b1, Y, MM, HH, DD, 5);
  // 4) out = Y @ W2 + b2, fp32       (gridDim.x = 8  -> lognx = 3)
  gemm_bt<0, float><<<dim3(DD / 128, MM / 128), dim3(256), 0, stream>>>(Y, W2t, b2, out, MM, DD, HH, 3);
}